// Round 11
// baseline (373.789 us; speedup 1.0000x reference)
//
#include <hip/hip_runtime.h>
#include <math.h>

#define DIM 32
#define BLK 256
#define JSPLIT 16   // j-chunks -> grid.y ; 16 fp64-atomic writers per out row
#define RI   2      // i-tiles per wave (32 rows) -> 512 pairs per wave-jtile
#define ITPB (4*RI) // i-tiles per block (8 tiles = 128 rows)
#define GTT  16     // j-tiles between fp32->fp64 flushes (256 j); 16%4==0 for slots

typedef _Float16 half8 __attribute__((ext_vector_type(8)));
typedef float    f32x4 __attribute__((ext_vector_type(4)));
typedef float    f32x2 __attribute__((ext_vector_type(2)));

struct hl16 { half8 h; half8 l; };   // 32 B fragment record (hi + lo plane)

// out[i] = 2^(c2*||x_i||^2) * sum_j 2^(bfq_j*2^-12 + <mf*x_i, y_j>)
//   c2 = -ls*log2(e) (fp64, exact per-i factor applied by the LAST block)
//   f16 hi/lo split (lo plane *2^12 to stay f16-normal):
//     cm = Ah*Bh ; cl = Ah*Bl + (Al*Bh + bfq) ; f = pk_fma(cl, 2^-12, cm)
//   exp2 = v_exp_f32 (issue-occupancy ~16cyc/wave64 dominates: 128cyc/step);
//   fp32 partials -> fp64 every GTT tiles; fp64 atomics; completion-counter
//   fused output (last of JSPLIT blocks per row-group writes out).
// R10: packed epilogue (R4-proven), bfq pre-scaled in prep (no per-tile mul),
//   distance-2 prefetch in 4 static slots (vmcnt waits off critical path),
//   rbf_finish fused via cnt[] (one fewer launch).

__global__ __launch_bounds__(BLK) void rbf_prep(
    const float* __restrict__ lsp, const float* __restrict__ x,
    const float* __restrict__ y, int n, int m,
    double* __restrict__ acc, double* __restrict__ scale,
    float* __restrict__ bfq, hl16* __restrict__ xhl, hl16* __restrict__ yhl,
    int* __restrict__ cnt)
{
    int i = blockIdx.x * BLK + threadIdx.x;
    const double c2 = -(double)lsp[0] * 1.4426950408889634074; // -ls*log2(e)
    const float mf = (float)(-2.0 * c2);
    if (i < n / (16 * ITPB)) cnt[i] = 0;   // completion counters for main
    if (i < n) {
        const float* xp = x + (size_t)i * DIM;
        double xs = 0.0;
        #pragma unroll
        for (int d = 0; d < DIM; ++d) { double v = (double)xp[d]; xs = fma(v, v, xs); }
        acc[i] = 0.0;
        scale[i] = exp2(c2 * xs);
        const int it = i >> 4, r15 = i & 15;
        #pragma unroll
        for (int q = 0; q < 4; ++q) {
            half8 hh, hl;
            #pragma unroll
            for (int d = 0; d < 8; ++d) {
                float v = xp[q * 8 + d] * mf;
                _Float16 h = (_Float16)v;
                hh[d] = h;
                hl[d] = (_Float16)((v - (float)h) * 4096.0f);
            }
            xhl[it * 64 + q * 16 + r15].h = hh;
            xhl[it * 64 + q * 16 + r15].l = hl;
        }
    }
    if (i < m) {
        const float* yp = y + (size_t)i * DIM;
        double ys = 0.0;
        #pragma unroll
        for (int d = 0; d < DIM; ++d) { double v = (double)yp[d]; ys = fma(v, v, ys); }
        bfq[i] = (float)(c2 * ys) * 4096.0f;   // pre-scaled by 2^12 (exact)
        const int it = i >> 4, r15 = i & 15;
        #pragma unroll
        for (int q = 0; q < 4; ++q) {
            half8 hh, hl;
            #pragma unroll
            for (int d = 0; d < 8; ++d) {
                float v = yp[q * 8 + d];
                _Float16 h = (_Float16)v;
                hh[d] = h;
                hl[d] = (_Float16)((v - (float)h) * 4096.0f);
            }
            yhl[it * 64 + q * 16 + r15].h = hh;
            yhl[it * 64 + q * 16 + r15].l = hl;
        }
    }
}

__global__ __launch_bounds__(BLK, 3) void rbf_main(
    const hl16* __restrict__ xhl, const hl16* __restrict__ yhl,
    const float* __restrict__ bfq, const double* __restrict__ scale,
    double* __restrict__ acc, int* __restrict__ cnt,
    float* __restrict__ out, int chunk_j)
{
    const int lane = threadIdx.x & 63;
    const int wave = threadIdx.x >> 6;
    const int itbase = blockIdx.x * ITPB + wave * RI;
    const int c15 = lane & 15;

    half8 ah[RI], al[RI];
    #pragma unroll
    for (int r = 0; r < RI; ++r) {
        ah[r] = xhl[(itbase + r) * 64 + lane].h;
        al[r] = xhl[(itbase + r) * 64 + lane].l;
    }

    const int jt0 = (blockIdx.y * chunk_j) >> 4;
    const int njt = chunk_j >> 4;                 // 128 j-tiles per chunk

    const f32x4 zq = {0.0f, 0.0f, 0.0f, 0.0f};    // persistent zero C quad
    const float k12 = 0x1p-12f;

    double accd[RI][4];
    #pragma unroll
    for (int r = 0; r < RI; ++r)
        #pragma unroll
        for (int e = 0; e < 4; ++e) accd[r][e] = 0.0;

    // 4-slot, distance-2 prefetch. tile s -> slot s&3 (g*GTT%4==0 so tt&3
    // is compile-time). Prefetch of tiles njt, njt+1 reads up to 2 tiles
    // past the chunk — never consumed; ws layout keeps strays inside d_ws.
    const hl16*  __restrict__ ybase = yhl + (size_t)jt0 * 64;
    const float* __restrict__ bbase = bfq + jt0 * 16;

    half8 bh[4], bl[4];
    float bq[4];
    bh[0] = ybase[lane].h;      bl[0] = ybase[lane].l;      bq[0] = bbase[c15];
    bh[1] = ybase[64 + lane].h; bl[1] = ybase[64 + lane].l; bq[1] = bbase[16 + c15];

    for (int g = 0; g < njt / GTT; ++g) {
        f32x2 accf[RI][2];
        #pragma unroll
        for (int r = 0; r < RI; ++r) {
            accf[r][0] = (f32x2){0.0f, 0.0f};
            accf[r][1] = (f32x2){0.0f, 0.0f};
        }

        #pragma unroll
        for (int tt = 0; tt < GTT; ++tt) {
            const int sc = tt & 3;                // consume slot (compile-time)
            const int sp = (tt + 2) & 3;          // prefetch slot (compile-time)
            const int pidx = g * GTT + tt + 2;    // tile to prefetch
            bh[sp] = ybase[(size_t)pidx * 64 + lane].h;
            bl[sp] = ybase[(size_t)pidx * 64 + lane].l;
            bq[sp] = bbase[pidx * 16 + c15];

            const f32x4 bqq = {bq[sc], bq[sc], bq[sc], bq[sc]};
            #pragma unroll
            for (int r = 0; r < RI; ++r) {
                f32x4 cm = __builtin_amdgcn_mfma_f32_16x16x32_f16(ah[r], bh[sc], zq, 0, 0, 0);
                f32x4 cl = __builtin_amdgcn_mfma_f32_16x16x32_f16(al[r], bh[sc], bqq, 0, 0, 0);
                cl = __builtin_amdgcn_mfma_f32_16x16x32_f16(ah[r], bl[sc], cl, 0, 0, 0);
                f32x2 cm01 = {cm[0], cm[1]}, cm23 = {cm[2], cm[3]};
                f32x2 cl01 = {cl[0], cl[1]}, cl23 = {cl[2], cl[3]};
                f32x2 f01 = cl01 * k12 + cm01;     // v_pk_fma_f32
                f32x2 f23 = cl23 * k12 + cm23;
                f32x2 e01 = {__builtin_amdgcn_exp2f(f01.x), __builtin_amdgcn_exp2f(f01.y)};
                f32x2 e23 = {__builtin_amdgcn_exp2f(f23.x), __builtin_amdgcn_exp2f(f23.y)};
                accf[r][0] += e01;                 // v_pk_add_f32
                accf[r][1] += e23;
            }
        }
        #pragma unroll
        for (int r = 0; r < RI; ++r) {
            accd[r][0] += (double)accf[r][0].x;
            accd[r][1] += (double)accf[r][0].y;
            accd[r][2] += (double)accf[r][1].x;
            accd[r][3] += (double)accf[r][1].y;
        }
    }

    // sum the 16 j-columns: fp64 butterfly across the 16-lane col groups
    #pragma unroll
    for (int r = 0; r < RI; ++r) {
        #pragma unroll
        for (int e = 0; e < 4; ++e) {
            double v = accd[r][e];
            v += __shfl_xor(v, 1, 64);
            v += __shfl_xor(v, 2, 64);
            v += __shfl_xor(v, 4, 64);
            v += __shfl_xor(v, 8, 64);
            if (c15 == 0) {
                int row = (itbase + r) * 16 + (lane >> 4) * 4 + e;
                atomicAdd(&acc[row], v);   // fp64, JSPLIT writers per row
            }
        }
    }

    // fused finish: last of the JSPLIT blocks for this row-group writes out
    __shared__ int lastflag;
    __syncthreads();                        // all atomicAdds of this block issued
    if (threadIdx.x == 0) {
        __threadfence();                    // release our adds device-wide
        int old = atomicAdd(&cnt[blockIdx.x], 1);
        lastflag = (old == JSPLIT - 1);
    }
    __syncthreads();
    if (lastflag) {
        __threadfence();                    // acquire others' adds
        const int rbase = blockIdx.x * (16 * ITPB);
        if (threadIdx.x < 16 * ITPB) {
            const int row = rbase + threadIdx.x;
            double a = atomicAdd(&acc[row], 0.0);   // coherent read of final sum
            out[row] = (float)(a * scale[row]);
        }
    }
}

extern "C" void kernel_launch(void* const* d_in, const int* in_sizes, int n_in,
                              void* d_out, int out_size, void* d_ws, size_t ws_size,
                              hipStream_t stream)
{
    const float* ls = (const float*)d_in[0];
    const float* x  = (const float*)d_in[1];
    const float* y  = (const float*)d_in[2];
    const int n = in_sizes[1] / DIM;   // 32768
    const int m = in_sizes[2] / DIM;   // 32768
    float* out = (float*)d_out;

    // ws layout (ORDER MATTERS — one-past-end prefetches must stay in ws):
    //   acc[n] f64 | scale[n] f64 | bfq[m] f32 | yhl | xhl | cnt  (~8.6 MB)
    char* ws = (char*)d_ws;
    double* acc   = (double*)ws;
    double* scale = acc + n;
    float*  bfq   = (float*)(scale + n);
    hl16*   yhl   = (hl16*)(bfq + m);
    hl16*   xhl   = yhl + (size_t)(m / 16) * 64;
    int*    cnt   = (int*)(xhl + (size_t)(n / 16) * 64);

    const int nm = (n > m) ? n : m;
    rbf_prep<<<(nm + BLK - 1) / BLK, BLK, 0, stream>>>(
        ls, x, y, n, m, acc, scale, bfq, xhl, yhl, cnt);

    const int chunk = m / JSPLIT;                 // 2048
    dim3 grid(n / (16 * ITPB), JSPLIT);           // 256 x 16
    rbf_main<<<grid, BLK, 0, stream>>>(xhl, yhl, bfq, scale, acc, cnt, out, chunk);
}

// Round 12
// 370.910 us; speedup vs baseline: 1.0078x; 1.0078x over previous
//
#include <hip/hip_runtime.h>
#include <math.h>

#define DIM 32
#define BLK 256
#define JSPLIT 16   // j-chunks -> grid.y ; 16 fp64-atomic writers per out row
#define RI   2      // i-tiles per wave (32 rows) -> 512 pairs per wave-jtile
#define ITPB (4*RI) // i-tiles per block (8 tiles = 128 rows)
#define GTT  32     // j-tiles between fp32->fp64 flushes (512 j)

typedef _Float16 half8 __attribute__((ext_vector_type(8)));
typedef float    f32x4 __attribute__((ext_vector_type(4)));
typedef float    f32x2 __attribute__((ext_vector_type(2)));

struct hl16 { half8 h; half8 l; };   // 32 B fragment record (hi + lo plane)

// out[i] = 2^(c2*||x_i||^2) * sum_j 2^(bfq_j*2^-12 + <mf*x_i, y_j>)
//   c2 = -ls*log2(e) (fp64, exact per-i factor applied by the LAST block)
//   f16 hi/lo split (lo plane *2^12 to stay f16-normal):
//     cm = Ah*Bh ; cl = Ah*Bl + (Al*Bh + bfq) ; f = pk_fma(cl, 2^-12, cm)
//   exp2 = v_exp_f32; fp32 partials -> fp64 every GTT tiles; fp64 atomics.
// R11 = R9's K-loop (2-slot parity prefetch — R10's 4-slot B state spilled
//   to AGPRs and serialized every load on vmcnt+accvgpr_write; 2 slots fit
//   arch VGPRs) + packed epilogue (R10-proven: issue 211->170 cyc/step) +
//   bfq pre-scaled in prep + completion-counter fused finish.

__global__ __launch_bounds__(BLK) void rbf_prep(
    const float* __restrict__ lsp, const float* __restrict__ x,
    const float* __restrict__ y, int n, int m,
    double* __restrict__ acc, double* __restrict__ scale,
    float* __restrict__ bfq, hl16* __restrict__ xhl, hl16* __restrict__ yhl,
    int* __restrict__ cnt)
{
    int i = blockIdx.x * BLK + threadIdx.x;
    const double c2 = -(double)lsp[0] * 1.4426950408889634074; // -ls*log2(e)
    const float mf = (float)(-2.0 * c2);
    if (i < n / (16 * ITPB)) cnt[i] = 0;   // completion counters for main
    if (i < n) {
        const float* xp = x + (size_t)i * DIM;
        double xs = 0.0;
        #pragma unroll
        for (int d = 0; d < DIM; ++d) { double v = (double)xp[d]; xs = fma(v, v, xs); }
        acc[i] = 0.0;
        scale[i] = exp2(c2 * xs);
        const int it = i >> 4, r15 = i & 15;
        #pragma unroll
        for (int q = 0; q < 4; ++q) {
            half8 hh, hl;
            #pragma unroll
            for (int d = 0; d < 8; ++d) {
                float v = xp[q * 8 + d] * mf;
                _Float16 h = (_Float16)v;
                hh[d] = h;
                hl[d] = (_Float16)((v - (float)h) * 4096.0f);
            }
            xhl[it * 64 + q * 16 + r15].h = hh;
            xhl[it * 64 + q * 16 + r15].l = hl;
        }
    }
    if (i < m) {
        const float* yp = y + (size_t)i * DIM;
        double ys = 0.0;
        #pragma unroll
        for (int d = 0; d < DIM; ++d) { double v = (double)yp[d]; ys = fma(v, v, ys); }
        bfq[i] = (float)(c2 * ys) * 4096.0f;   // pre-scaled by 2^12 (exact)
        const int it = i >> 4, r15 = i & 15;
        #pragma unroll
        for (int q = 0; q < 4; ++q) {
            half8 hh, hl;
            #pragma unroll
            for (int d = 0; d < 8; ++d) {
                float v = yp[q * 8 + d];
                _Float16 h = (_Float16)v;
                hh[d] = h;
                hl[d] = (_Float16)((v - (float)h) * 4096.0f);
            }
            yhl[it * 64 + q * 16 + r15].h = hh;
            yhl[it * 64 + q * 16 + r15].l = hl;
        }
    }
}

__global__ __launch_bounds__(BLK, 3) void rbf_main(
    const hl16* __restrict__ xhl, const hl16* __restrict__ yhl,
    const float* __restrict__ bfq, const double* __restrict__ scale,
    double* __restrict__ acc, int* __restrict__ cnt,
    float* __restrict__ out, int chunk_j)
{
    const int lane = threadIdx.x & 63;
    const int wave = threadIdx.x >> 6;
    const int itbase = blockIdx.x * ITPB + wave * RI;
    const int c15 = lane & 15;

    half8 ah[RI], al[RI];
    #pragma unroll
    for (int r = 0; r < RI; ++r) {
        ah[r] = xhl[(itbase + r) * 64 + lane].h;
        al[r] = xhl[(itbase + r) * 64 + lane].l;
    }

    const int jt0 = (blockIdx.y * chunk_j) >> 4;
    const int njt = chunk_j >> 4;                 // 128 j-tiles per chunk

    const f32x4 zq = {0.0f, 0.0f, 0.0f, 0.0f};    // persistent zero C quad
    const float k12 = 0x1p-12f;

    double accd[RI][4];
    #pragma unroll
    for (int r = 0; r < RI; ++r)
        #pragma unroll
        for (int e = 0; e < 4; ++e) accd[r][e] = 0.0;

    // 2-slot parity double-buffered B fragments (fits arch VGPRs — R10 lesson)
    half8 bh[2], bl[2];
    float bq[2];
    bh[0] = yhl[(size_t)jt0 * 64 + lane].h;
    bl[0] = yhl[(size_t)jt0 * 64 + lane].l;
    bq[0] = bfq[jt0 * 16 + c15];

    for (int g = 0; g < njt / GTT; ++g) {
        // per-group uniform bases; per-tile offsets are compile-time consts
        const hl16*  __restrict__ ygrp = yhl + ((size_t)jt0 + (size_t)g * GTT) * 64;
        const float* __restrict__ bgrp = bfq + (jt0 + g * GTT) * 16;

        f32x2 accf[RI][2];
        #pragma unroll
        for (int r = 0; r < RI; ++r) {
            accf[r][0] = (f32x2){0.0f, 0.0f};
            accf[r][1] = (f32x2){0.0f, 0.0f};
        }

        #pragma unroll
        for (int tt = 0; tt < GTT; ++tt) {
            const int cur = tt & 1, nxt = cur ^ 1;
            // prefetch tile tt+1 (last prefetch of the last group reads one
            // tile past the chunk — never consumed; ws layout keeps it in ws)
            bh[nxt] = ygrp[(tt + 1) * 64 + lane].h;
            bl[nxt] = ygrp[(tt + 1) * 64 + lane].l;
            bq[nxt] = bgrp[(tt + 1) * 16 + c15];

            const f32x4 bqq = {bq[cur], bq[cur], bq[cur], bq[cur]};
            #pragma unroll
            for (int r = 0; r < RI; ++r) {
                f32x4 cm = __builtin_amdgcn_mfma_f32_16x16x32_f16(ah[r], bh[cur], zq, 0, 0, 0);
                f32x4 cl = __builtin_amdgcn_mfma_f32_16x16x32_f16(al[r], bh[cur], bqq, 0, 0, 0);
                cl = __builtin_amdgcn_mfma_f32_16x16x32_f16(ah[r], bl[cur], cl, 0, 0, 0);
                f32x2 cm01 = {cm[0], cm[1]}, cm23 = {cm[2], cm[3]};
                f32x2 cl01 = {cl[0], cl[1]}, cl23 = {cl[2], cl[3]};
                f32x2 f01 = cl01 * k12 + cm01;     // v_pk_fma_f32
                f32x2 f23 = cl23 * k12 + cm23;
                f32x2 e01 = {__builtin_amdgcn_exp2f(f01.x), __builtin_amdgcn_exp2f(f01.y)};
                f32x2 e23 = {__builtin_amdgcn_exp2f(f23.x), __builtin_amdgcn_exp2f(f23.y)};
                accf[r][0] += e01;                 // v_pk_add_f32
                accf[r][1] += e23;
            }
        }
        #pragma unroll
        for (int r = 0; r < RI; ++r) {
            accd[r][0] += (double)accf[r][0].x;
            accd[r][1] += (double)accf[r][0].y;
            accd[r][2] += (double)accf[r][1].x;
            accd[r][3] += (double)accf[r][1].y;
        }
    }

    // sum the 16 j-columns: fp64 butterfly across the 16-lane col groups
    #pragma unroll
    for (int r = 0; r < RI; ++r) {
        #pragma unroll
        for (int e = 0; e < 4; ++e) {
            double v = accd[r][e];
            v += __shfl_xor(v, 1, 64);
            v += __shfl_xor(v, 2, 64);
            v += __shfl_xor(v, 4, 64);
            v += __shfl_xor(v, 8, 64);
            if (c15 == 0) {
                int row = (itbase + r) * 16 + (lane >> 4) * 4 + e;
                atomicAdd(&acc[row], v);   // fp64, JSPLIT writers per row
            }
        }
    }

    // fused finish: last of the JSPLIT blocks for this row-group writes out
    __shared__ int lastflag;
    __syncthreads();                        // all atomicAdds of this block issued
    if (threadIdx.x == 0) {
        __threadfence();                    // release our adds device-wide
        int old = atomicAdd(&cnt[blockIdx.x], 1);
        lastflag = (old == JSPLIT - 1);
    }
    __syncthreads();
    if (lastflag) {
        __threadfence();                    // acquire others' adds
        const int rbase = blockIdx.x * (16 * ITPB);
        if (threadIdx.x < 16 * ITPB) {
            const int row = rbase + threadIdx.x;
            double a = atomicAdd(&acc[row], 0.0);   // coherent read of final sum
            out[row] = (float)(a * scale[row]);
        }
    }
}

extern "C" void kernel_launch(void* const* d_in, const int* in_sizes, int n_in,
                              void* d_out, int out_size, void* d_ws, size_t ws_size,
                              hipStream_t stream)
{
    const float* ls = (const float*)d_in[0];
    const float* x  = (const float*)d_in[1];
    const float* y  = (const float*)d_in[2];
    const int n = in_sizes[1] / DIM;   // 32768
    const int m = in_sizes[2] / DIM;   // 32768
    float* out = (float*)d_out;

    // ws layout (ORDER MATTERS — one-past-end prefetches must stay in ws):
    //   acc[n] f64 | scale[n] f64 | bfq[m] f32 | yhl | xhl | cnt  (~8.6 MB)
    char* ws = (char*)d_ws;
    double* acc   = (double*)ws;
    double* scale = acc + n;
    float*  bfq   = (float*)(scale + n);
    hl16*   yhl   = (hl16*)(bfq + m);
    hl16*   xhl   = yhl + (size_t)(m / 16) * 64;
    int*    cnt   = (int*)(xhl + (size_t)(n / 16) * 64);

    const int nm = (n > m) ? n : m;
    rbf_prep<<<(nm + BLK - 1) / BLK, BLK, 0, stream>>>(
        ls, x, y, n, m, acc, scale, bfq, xhl, yhl, cnt);

    const int chunk = m / JSPLIT;                 // 2048
    dim3 grid(n / (16 * ITPB), JSPLIT);           // 256 x 16
    rbf_main<<<grid, BLK, 0, stream>>>(xhl, yhl, bfq, scale, acc, cnt, out, chunk);
}

// Round 13
// 362.151 us; speedup vs baseline: 1.0321x; 1.0242x over previous
//
#include <hip/hip_runtime.h>
#include <math.h>

#define DIM 32
#define BLK 256
#define JSPLIT 16   // j-chunks -> grid.y ; 16 fp64-atomic writers per out row
#define RI   2      // i-tiles per wave (32 rows) -> 512 pairs per wave-jtile
#define ITPB (4*RI) // i-tiles per block (8 tiles = 128 rows)
#define GTT  32     // j-tiles between fp32->fp64 flushes (512 j)

typedef _Float16 half8 __attribute__((ext_vector_type(8)));
typedef float    f32x4 __attribute__((ext_vector_type(4)));

struct hl16 { half8 h; half8 l; };   // 32 B fragment record (hi + lo plane)

// out[i] = 2^(c2*||x_i||^2) * sum_j 2^(bf_j + <mf*x_i, y_j>)
//   c2 = -ls*log2(e) (fp64, exact per-i factor applied by the LAST block)
//   f16 hi/lo split (lo plane *2^12 to stay f16-normal):
//     cm = Ah*Bh ; cl = Ah*Bl + (Al*Bh + bf*2^12) ; f = fma(cl, 2^-12, cm)
//   exp2 = v_exp_f32; fp32 partials -> fp64 every GTT tiles; fp64 atomics.
// R12 = EXACT R9 kernel body (scalar epilogue — R10/R11's packed f32x2
//   epilogue regressed 237->347 via stall explosion; scalar's 8 independent
//   chains schedule better) + completion-counter fused finish ONLY
//   (single-variable test of the fusion; saves the 3rd launch).

__global__ __launch_bounds__(BLK) void rbf_prep(
    const float* __restrict__ lsp, const float* __restrict__ x,
    const float* __restrict__ y, int n, int m,
    double* __restrict__ acc, double* __restrict__ scale,
    float* __restrict__ bf, hl16* __restrict__ xhl, hl16* __restrict__ yhl,
    int* __restrict__ cnt)
{
    int i = blockIdx.x * BLK + threadIdx.x;
    const double c2 = -(double)lsp[0] * 1.4426950408889634074; // -ls*log2(e)
    const float mf = (float)(-2.0 * c2);
    if (i < n / (16 * ITPB)) cnt[i] = 0;   // completion counters for main
    if (i < n) {
        const float* xp = x + (size_t)i * DIM;
        double xs = 0.0;
        #pragma unroll
        for (int d = 0; d < DIM; ++d) { double v = (double)xp[d]; xs = fma(v, v, xs); }
        acc[i] = 0.0;
        scale[i] = exp2(c2 * xs);
        const int it = i >> 4, r15 = i & 15;
        #pragma unroll
        for (int q = 0; q < 4; ++q) {
            half8 hh, hl;
            #pragma unroll
            for (int d = 0; d < 8; ++d) {
                float v = xp[q * 8 + d] * mf;
                _Float16 h = (_Float16)v;
                hh[d] = h;
                hl[d] = (_Float16)((v - (float)h) * 4096.0f);
            }
            xhl[it * 64 + q * 16 + r15].h = hh;
            xhl[it * 64 + q * 16 + r15].l = hl;
        }
    }
    if (i < m) {
        const float* yp = y + (size_t)i * DIM;
        double ys = 0.0;
        #pragma unroll
        for (int d = 0; d < DIM; ++d) { double v = (double)yp[d]; ys = fma(v, v, ys); }
        bf[i] = (float)(c2 * ys);
        const int it = i >> 4, r15 = i & 15;
        #pragma unroll
        for (int q = 0; q < 4; ++q) {
            half8 hh, hl;
            #pragma unroll
            for (int d = 0; d < 8; ++d) {
                float v = yp[q * 8 + d];
                _Float16 h = (_Float16)v;
                hh[d] = h;
                hl[d] = (_Float16)((v - (float)h) * 4096.0f);
            }
            yhl[it * 64 + q * 16 + r15].h = hh;
            yhl[it * 64 + q * 16 + r15].l = hl;
        }
    }
}

__global__ __launch_bounds__(BLK, 3) void rbf_main(
    const hl16* __restrict__ xhl, const hl16* __restrict__ yhl,
    const float* __restrict__ bf, const double* __restrict__ scale,
    double* __restrict__ acc, int* __restrict__ cnt,
    float* __restrict__ out, int chunk_j)
{
    const int lane = threadIdx.x & 63;
    const int wave = threadIdx.x >> 6;
    const int itbase = blockIdx.x * ITPB + wave * RI;
    const int c15 = lane & 15;

    half8 ah[RI], al[RI];
    #pragma unroll
    for (int r = 0; r < RI; ++r) {
        ah[r] = xhl[(itbase + r) * 64 + lane].h;
        al[r] = xhl[(itbase + r) * 64 + lane].l;
    }

    const int jt0 = (blockIdx.y * chunk_j) >> 4;
    const int njt = chunk_j >> 4;                 // 128 j-tiles per chunk

    const f32x4 zq = {0.0f, 0.0f, 0.0f, 0.0f};    // persistent zero C quad
    const float k12 = 0x1p-12f;

    double accd[RI][4];
    #pragma unroll
    for (int r = 0; r < RI; ++r)
        #pragma unroll
        for (int e = 0; e < 4; ++e) accd[r][e] = 0.0;

    // 2-slot parity double-buffered B fragments
    half8 bh[2], bl[2];
    float bfv[2];
    bh[0] = yhl[(size_t)jt0 * 64 + lane].h;
    bl[0] = yhl[(size_t)jt0 * 64 + lane].l;
    bfv[0] = bf[jt0 * 16 + c15];

    for (int g = 0; g < njt / GTT; ++g) {
        // per-group uniform bases; per-tile offsets are compile-time consts
        const hl16*  __restrict__ ygrp = yhl + ((size_t)jt0 + (size_t)g * GTT) * 64;
        const float* __restrict__ bgrp = bf + (jt0 + g * GTT) * 16;

        float accf[RI][4];
        #pragma unroll
        for (int r = 0; r < RI; ++r)
            #pragma unroll
            for (int e = 0; e < 4; ++e) accf[r][e] = 0.0f;

        #pragma unroll
        for (int tt = 0; tt < GTT; ++tt) {
            const int cur = tt & 1, nxt = cur ^ 1;
            // prefetch tile tt+1 (last prefetch of the last group reads one
            // tile past the chunk — never consumed; ws layout keeps it in ws)
            bh[nxt] = ygrp[(tt + 1) * 64 + lane].h;
            bl[nxt] = ygrp[(tt + 1) * 64 + lane].l;
            bfv[nxt] = bgrp[(tt + 1) * 16 + c15];

            // bf*2^12 splat as the cl-chain C-init (shared across r)
            const float bq1 = bfv[cur] * 4096.0f;
            const f32x4 bq = {bq1, bq1, bq1, bq1};

            #pragma unroll
            for (int r = 0; r < RI; ++r) {
                f32x4 cm = __builtin_amdgcn_mfma_f32_16x16x32_f16(ah[r], bh[cur], zq, 0, 0, 0);
                f32x4 cl = __builtin_amdgcn_mfma_f32_16x16x32_f16(al[r], bh[cur], bq, 0, 0, 0);
                cl = __builtin_amdgcn_mfma_f32_16x16x32_f16(ah[r], bl[cur], cl, 0, 0, 0);
                #pragma unroll
                for (int e = 0; e < 4; ++e) {
                    float f = __builtin_fmaf(cl[e], k12, cm[e]);
                    accf[r][e] += __builtin_amdgcn_exp2f(f);
                }
            }
        }
        #pragma unroll
        for (int r = 0; r < RI; ++r)
            #pragma unroll
            for (int e = 0; e < 4; ++e) accd[r][e] += (double)accf[r][e];
    }

    // sum the 16 j-columns: fp64 butterfly across the 16-lane col groups
    #pragma unroll
    for (int r = 0; r < RI; ++r) {
        #pragma unroll
        for (int e = 0; e < 4; ++e) {
            double v = accd[r][e];
            v += __shfl_xor(v, 1, 64);
            v += __shfl_xor(v, 2, 64);
            v += __shfl_xor(v, 4, 64);
            v += __shfl_xor(v, 8, 64);
            if (c15 == 0) {
                int row = (itbase + r) * 16 + (lane >> 4) * 4 + e;
                atomicAdd(&acc[row], v);   // fp64, JSPLIT writers per row
            }
        }
    }

    // fused finish: last of the JSPLIT blocks for this row-group writes out
    __shared__ int lastflag;
    __syncthreads();                        // all atomicAdds of this block issued
    if (threadIdx.x == 0) {
        __threadfence();                    // release our adds device-wide
        int old = atomicAdd(&cnt[blockIdx.x], 1);
        lastflag = (old == JSPLIT - 1);
    }
    __syncthreads();
    if (lastflag) {
        __threadfence();                    // acquire others' adds
        const int rbase = blockIdx.x * (16 * ITPB);
        if (threadIdx.x < 16 * ITPB) {
            const int row = rbase + threadIdx.x;
            double a = atomicAdd(&acc[row], 0.0);   // coherent read of final sum
            out[row] = (float)(a * scale[row]);
        }
    }
}

extern "C" void kernel_launch(void* const* d_in, const int* in_sizes, int n_in,
                              void* d_out, int out_size, void* d_ws, size_t ws_size,
                              hipStream_t stream)
{
    const float* ls = (const float*)d_in[0];
    const float* x  = (const float*)d_in[1];
    const float* y  = (const float*)d_in[2];
    const int n = in_sizes[1] / DIM;   // 32768
    const int m = in_sizes[2] / DIM;   // 32768
    float* out = (float*)d_out;

    // ws layout (ORDER MATTERS — one-past-end prefetches must stay in ws):
    //   acc[n] f64 | scale[n] f64 | bf[m] f32 | yhl | xhl | cnt  (~8.6 MB)
    char* ws = (char*)d_ws;
    double* acc   = (double*)ws;
    double* scale = acc + n;
    float*  bf    = (float*)(scale + n);
    hl16*   yhl   = (hl16*)(bf + m);
    hl16*   xhl   = yhl + (size_t)(m / 16) * 64;
    int*    cnt   = (int*)(xhl + (size_t)(n / 16) * 64);

    const int nm = (n > m) ? n : m;
    rbf_prep<<<(nm + BLK - 1) / BLK, BLK, 0, stream>>>(
        ls, x, y, n, m, acc, scale, bf, xhl, yhl, cnt);

    const int chunk = m / JSPLIT;                 // 2048
    dim3 grid(n / (16 * ITPB), JSPLIT);           // 256 x 16
    rbf_main<<<grid, BLK, 0, stream>>>(xhl, yhl, bf, scale, acc, cnt, out, chunk);
}

// Round 14
// 295.944 us; speedup vs baseline: 1.2630x; 1.2237x over previous
//
#include <hip/hip_runtime.h>
#include <math.h>

#define DIM 32
#define BLK 256
#define JSPLIT 16   // j-chunks -> grid.y ; 16 fp64-atomic writers per out row
#define RI   2      // i-tiles per wave (32 rows) -> 512 pairs per wave-jtile
#define ITPB (4*RI) // i-tiles per block (8 tiles = 128 rows)
#define GTT  32     // j-tiles between fp32->fp64 flushes (512 j)

typedef _Float16 half8 __attribute__((ext_vector_type(8)));
typedef float    f32x4 __attribute__((ext_vector_type(4)));

struct hl16 { half8 h; half8 l; };   // 32 B fragment record (hi + lo plane)

// out[i] = 2^(c2*||x_i||^2) * sum_j 2^(bf_j + <mf*x_i, y_j>)
//   c2 = -ls*log2(e) (fp64, exact per-i factor in fp64 epilogue kernel)
//   f16 hi/lo split (lo plane *2^12 to stay f16-normal):
//     cm = Ah*Bh ; cl = Ah*Bl + (Al*Bh + bf*2^12) ; f = fma(cl, 2^-12, cm)
//   exp2 = v_exp_f32; fp32 partials -> fp64 every GTT tiles; fp64 atomics.
// R13 = R9 (best: 237 us main / 294 total) + uniform-pointer-bump B loads:
//   fixed per-lane vaddr, wave-uniform base bumped 1 tile/step on the
//   scalar pipe; all load offsets are imm {0,16,2048,2064} <= 4095.
//   Fused finish REVERTED (R12 convicted it: +76 us via threadfence L2
//   pollution). Packed epilogue REVERTED (R10/R11: +35 us stalls).

__global__ __launch_bounds__(BLK) void rbf_prep(
    const float* __restrict__ lsp, const float* __restrict__ x,
    const float* __restrict__ y, int n, int m,
    double* __restrict__ acc, double* __restrict__ scale,
    float* __restrict__ bf, hl16* __restrict__ xhl, hl16* __restrict__ yhl)
{
    int i = blockIdx.x * BLK + threadIdx.x;
    const double c2 = -(double)lsp[0] * 1.4426950408889634074; // -ls*log2(e)
    const float mf = (float)(-2.0 * c2);
    if (i < n) {
        const float* xp = x + (size_t)i * DIM;
        double xs = 0.0;
        #pragma unroll
        for (int d = 0; d < DIM; ++d) { double v = (double)xp[d]; xs = fma(v, v, xs); }
        acc[i] = 0.0;
        scale[i] = exp2(c2 * xs);
        const int it = i >> 4, r15 = i & 15;
        #pragma unroll
        for (int q = 0; q < 4; ++q) {
            half8 hh, hl;
            #pragma unroll
            for (int d = 0; d < 8; ++d) {
                float v = xp[q * 8 + d] * mf;
                _Float16 h = (_Float16)v;
                hh[d] = h;
                hl[d] = (_Float16)((v - (float)h) * 4096.0f);
            }
            xhl[it * 64 + q * 16 + r15].h = hh;
            xhl[it * 64 + q * 16 + r15].l = hl;
        }
    }
    if (i < m) {
        const float* yp = y + (size_t)i * DIM;
        double ys = 0.0;
        #pragma unroll
        for (int d = 0; d < DIM; ++d) { double v = (double)yp[d]; ys = fma(v, v, ys); }
        bf[i] = (float)(c2 * ys);
        const int it = i >> 4, r15 = i & 15;
        #pragma unroll
        for (int q = 0; q < 4; ++q) {
            half8 hh, hl;
            #pragma unroll
            for (int d = 0; d < 8; ++d) {
                float v = yp[q * 8 + d];
                _Float16 h = (_Float16)v;
                hh[d] = h;
                hl[d] = (_Float16)((v - (float)h) * 4096.0f);
            }
            yhl[it * 64 + q * 16 + r15].h = hh;
            yhl[it * 64 + q * 16 + r15].l = hl;
        }
    }
}

__global__ __launch_bounds__(BLK, 3) void rbf_main(
    const hl16* __restrict__ xhl, const hl16* __restrict__ yhl,
    const float* __restrict__ bf, double* __restrict__ acc, int chunk_j)
{
    const int lane = threadIdx.x & 63;
    const int wave = threadIdx.x >> 6;
    const int itbase = blockIdx.x * ITPB + wave * RI;
    const int c15 = lane & 15;

    half8 ah[RI], al[RI];
    #pragma unroll
    for (int r = 0; r < RI; ++r) {
        ah[r] = xhl[(itbase + r) * 64 + lane].h;
        al[r] = xhl[(itbase + r) * 64 + lane].l;
    }

    const int jt0 = (blockIdx.y * chunk_j) >> 4;
    const int njt = chunk_j >> 4;                 // 128 j-tiles per chunk

    const f32x4 zq = {0.0f, 0.0f, 0.0f, 0.0f};    // persistent zero C quad
    const float k12 = 0x1p-12f;

    double accd[RI][4];
    #pragma unroll
    for (int r = 0; r < RI; ++r)
        #pragma unroll
        for (int e = 0; e < 4; ++e) accd[r][e] = 0.0;

    // uniform-pointer-bump addressing: fixed per-lane vaddr; base pointers
    // bumped one tile per step (scalar pipe). Load offsets are imm
    // {0,16} (cur preload) and {2048,2064} (next-tile prefetch) — <= 4095.
    const hl16*  __restrict__ yp = yhl + (size_t)jt0 * 64;   // uniform base
    const float* __restrict__ bp = bf + jt0 * 16;            // uniform base

    // 2-slot parity double-buffered B fragments
    half8 bh[2], bl[2];
    float bfv[2];
    bh[0] = yp[lane].h;
    bl[0] = yp[lane].l;
    bfv[0] = bp[c15];

    for (int g = 0; g < njt / GTT; ++g) {
        float accf[RI][4];
        #pragma unroll
        for (int r = 0; r < RI; ++r)
            #pragma unroll
            for (int e = 0; e < 4; ++e) accf[r][e] = 0.0f;

        #pragma unroll
        for (int tt = 0; tt < GTT; ++tt) {
            const int cur = tt & 1, nxt = cur ^ 1;
            // prefetch next tile: imm offset 2048 (h) / 2064 (l) / 64 (bf).
            // Last prefetch of the last group reads one tile past the chunk
            // — never consumed; ws layout keeps the stray inside d_ws.
            bh[nxt] = yp[64 + lane].h;
            bl[nxt] = yp[64 + lane].l;
            bfv[nxt] = bp[16 + c15];

            // bf*2^12 splat as the cl-chain C-init (shared across r)
            const float bq1 = bfv[cur] * 4096.0f;
            const f32x4 bq = {bq1, bq1, bq1, bq1};

            #pragma unroll
            for (int r = 0; r < RI; ++r) {
                f32x4 cm = __builtin_amdgcn_mfma_f32_16x16x32_f16(ah[r], bh[cur], zq, 0, 0, 0);
                f32x4 cl = __builtin_amdgcn_mfma_f32_16x16x32_f16(al[r], bh[cur], bq, 0, 0, 0);
                cl = __builtin_amdgcn_mfma_f32_16x16x32_f16(ah[r], bl[cur], cl, 0, 0, 0);
                #pragma unroll
                for (int e = 0; e < 4; ++e) {
                    float f = __builtin_fmaf(cl[e], k12, cm[e]);
                    accf[r][e] += __builtin_amdgcn_exp2f(f);
                }
            }
            yp += 64;   // one tile = 2048 B; uniform s_add on scalar pipe
            bp += 16;   // 64 B
        }
        #pragma unroll
        for (int r = 0; r < RI; ++r)
            #pragma unroll
            for (int e = 0; e < 4; ++e) accd[r][e] += (double)accf[r][e];
    }

    // sum the 16 j-columns: fp64 butterfly across the 16-lane col groups
    #pragma unroll
    for (int r = 0; r < RI; ++r) {
        #pragma unroll
        for (int e = 0; e < 4; ++e) {
            double v = accd[r][e];
            v += __shfl_xor(v, 1, 64);
            v += __shfl_xor(v, 2, 64);
            v += __shfl_xor(v, 4, 64);
            v += __shfl_xor(v, 8, 64);
            if (c15 == 0) {
                int row = (itbase + r) * 16 + (lane >> 4) * 4 + e;
                atomicAdd(&acc[row], v);   // fp64, JSPLIT writers per row
            }
        }
    }
}

__global__ __launch_bounds__(BLK) void rbf_finish(
    const double* __restrict__ acc, const double* __restrict__ scale,
    float* __restrict__ out, int n)
{
    int i = blockIdx.x * BLK + threadIdx.x;
    if (i < n) out[i] = (float)(acc[i] * scale[i]);
}

extern "C" void kernel_launch(void* const* d_in, const int* in_sizes, int n_in,
                              void* d_out, int out_size, void* d_ws, size_t ws_size,
                              hipStream_t stream)
{
    const float* ls = (const float*)d_in[0];
    const float* x  = (const float*)d_in[1];
    const float* y  = (const float*)d_in[2];
    const int n = in_sizes[1] / DIM;   // 32768
    const int m = in_sizes[2] / DIM;   // 32768
    float* out = (float*)d_out;

    // ws layout (ORDER MATTERS — one-past-end prefetches must stay in ws):
    //   acc[n] f64 | scale[n] f64 | bf[m] f32 | yhl | xhl   (~8.6 MB)
    char* ws = (char*)d_ws;
    double* acc   = (double*)ws;
    double* scale = acc + n;
    float*  bf    = (float*)(scale + n);
    hl16*   yhl   = (hl16*)(bf + m);
    hl16*   xhl   = yhl + (size_t)(m / 16) * 64;

    const int nm = (n > m) ? n : m;
    rbf_prep<<<(nm + BLK - 1) / BLK, BLK, 0, stream>>>(
        ls, x, y, n, m, acc, scale, bf, xhl, yhl);

    const int chunk = m / JSPLIT;                 // 2048
    dim3 grid(n / (16 * ITPB), JSPLIT);           // 256 x 16
    rbf_main<<<grid, BLK, 0, stream>>>(xhl, yhl, bf, acc, chunk);

    rbf_finish<<<(n + BLK - 1) / BLK, BLK, 0, stream>>>(acc, scale, out, n);
}

// Round 15
// 279.089 us; speedup vs baseline: 1.3393x; 1.0604x over previous
//
#include <hip/hip_runtime.h>
#include <math.h>

#define DIM 32
#define BLK 256
#define JSPLIT 16   // j-chunks -> grid.y ; 16 fp64-atomic writers per out row
#define RI   4      // i-tiles per wave (64 rows) -> 1024 pairs per wave-jtile
#define ITPB (4*RI) // i-tiles per block (16 tiles = 256 rows)
#define GTT  32     // j-tiles between fp32->fp64 flushes (512 j)

typedef _Float16 half8 __attribute__((ext_vector_type(8)));
typedef float    f32x4 __attribute__((ext_vector_type(4)));

struct hl16 { half8 h; half8 l; };   // 32 B fragment record (hi + lo plane)

// out[i] = 2^(c2*||x_i||^2) * sum_j pf_j * 2^(<mf*x_i, y_j> - 64)
//   where pf_j = 2^(c2*||y_j||^2 + 64)  (fp64-computed in prep, fp32 stored)
//   c2 = -ls*log2(e) (fp64, exact per-i factor in fp64 finish kernel)
//   f16 hi/lo split (lo plane *2^12 to stay f16-normal):
//     cm = Ah*Bh + (-64 quad) ; cl = Ah*Bl + Al*Bh ; f = fma(cl,2^-12,cm)
//     accf += exp2(f) * pf   (v_fmac; -64 bias makes 2^f overflow-proof,
//     relevant terms never reach the f<-126 flush)
//   fp32 partials -> fp64 every GTT tiles; fp64 atomics.
// R14 = R13 lean K-loop + RI=4 (B loads/MFMA-C-setup/flush amortize over
//   2x pairs; per-step issue 0.41 -> ~0.32 cyc/pair) at launch_bounds(256,2)
//   (256-reg budget so the ~145-reg live set stays in arch VGPRs — R5's
//   RI=4 failed at the 128-reg budget via AGPR churn) + bias-fold epilogue
//   (persistent -64 C-quad kills the per-step bf splat+mul entirely).

__global__ __launch_bounds__(BLK) void rbf_prep(
    const float* __restrict__ lsp, const float* __restrict__ x,
    const float* __restrict__ y, int n, int m,
    double* __restrict__ acc, double* __restrict__ scale,
    float* __restrict__ pf, hl16* __restrict__ xhl, hl16* __restrict__ yhl)
{
    int i = blockIdx.x * BLK + threadIdx.x;
    const double c2 = -(double)lsp[0] * 1.4426950408889634074; // -ls*log2(e)
    const float mf = (float)(-2.0 * c2);
    if (i < n) {
        const float* xp = x + (size_t)i * DIM;
        double xs = 0.0;
        #pragma unroll
        for (int d = 0; d < DIM; ++d) { double v = (double)xp[d]; xs = fma(v, v, xs); }
        acc[i] = 0.0;
        scale[i] = exp2(c2 * xs);
        const int it = i >> 4, r15 = i & 15;
        #pragma unroll
        for (int q = 0; q < 4; ++q) {
            half8 hh, hl;
            #pragma unroll
            for (int d = 0; d < 8; ++d) {
                float v = xp[q * 8 + d] * mf;
                _Float16 h = (_Float16)v;
                hh[d] = h;
                hl[d] = (_Float16)((v - (float)h) * 4096.0f);
            }
            xhl[it * 64 + q * 16 + r15].h = hh;
            xhl[it * 64 + q * 16 + r15].l = hl;
        }
    }
    if (i < m) {
        const float* yp = y + (size_t)i * DIM;
        double ys = 0.0;
        #pragma unroll
        for (int d = 0; d < DIM; ++d) { double v = (double)yp[d]; ys = fma(v, v, ys); }
        pf[i] = (float)exp2(c2 * ys + 64.0);   // 2^(bf+64), fp64-accurate
        const int it = i >> 4, r15 = i & 15;
        #pragma unroll
        for (int q = 0; q < 4; ++q) {
            half8 hh, hl;
            #pragma unroll
            for (int d = 0; d < 8; ++d) {
                float v = yp[q * 8 + d];
                _Float16 h = (_Float16)v;
                hh[d] = h;
                hl[d] = (_Float16)((v - (float)h) * 4096.0f);
            }
            yhl[it * 64 + q * 16 + r15].h = hh;
            yhl[it * 64 + q * 16 + r15].l = hl;
        }
    }
}

__global__ __launch_bounds__(BLK, 2) void rbf_main(
    const hl16* __restrict__ xhl, const hl16* __restrict__ yhl,
    const float* __restrict__ pfq, double* __restrict__ acc, int chunk_j)
{
    const int lane = threadIdx.x & 63;
    const int wave = threadIdx.x >> 6;
    const int itbase = blockIdx.x * ITPB + wave * RI;
    const int c15 = lane & 15;

    half8 ah[RI], al[RI];
    #pragma unroll
    for (int r = 0; r < RI; ++r) {
        ah[r] = xhl[(itbase + r) * 64 + lane].h;
        al[r] = xhl[(itbase + r) * 64 + lane].l;
    }

    const int jt0 = (blockIdx.y * chunk_j) >> 4;
    const int njt = chunk_j >> 4;                 // 128 j-tiles per chunk

    const f32x4 zq = {0.0f, 0.0f, 0.0f, 0.0f};            // persistent zero C
    const f32x4 nq = {-64.0f, -64.0f, -64.0f, -64.0f};    // persistent bias C
    const float k12 = 0x1p-12f;

    double accd[RI][4];
    #pragma unroll
    for (int r = 0; r < RI; ++r)
        #pragma unroll
        for (int e = 0; e < 4; ++e) accd[r][e] = 0.0;

    // uniform-pointer-bump addressing: fixed per-lane vaddr; bases bumped
    // one tile per step on the scalar pipe; load offsets imm {0,16,2048,2064}
    const hl16*  __restrict__ yp = yhl + (size_t)jt0 * 64;   // uniform base
    const float* __restrict__ bp = pfq + jt0 * 16;           // uniform base

    // 2-slot parity double-buffered B fragments
    half8 bh[2], bl[2];
    float pfv[2];
    bh[0] = yp[lane].h;
    bl[0] = yp[lane].l;
    pfv[0] = bp[c15];

    for (int g = 0; g < njt / GTT; ++g) {
        float accf[RI][4];
        #pragma unroll
        for (int r = 0; r < RI; ++r)
            #pragma unroll
            for (int e = 0; e < 4; ++e) accf[r][e] = 0.0f;

        #pragma unroll
        for (int tt = 0; tt < GTT; ++tt) {
            const int cur = tt & 1, nxt = cur ^ 1;
            // prefetch next tile (last prefetch of the last group reads one
            // tile past the chunk — never consumed; ws layout keeps it in ws)
            bh[nxt] = yp[64 + lane].h;
            bl[nxt] = yp[64 + lane].l;
            pfv[nxt] = bp[16 + c15];

            #pragma unroll
            for (int r = 0; r < RI; ++r) {
                f32x4 cm = __builtin_amdgcn_mfma_f32_16x16x32_f16(ah[r], bh[cur], nq, 0, 0, 0);
                f32x4 cl = __builtin_amdgcn_mfma_f32_16x16x32_f16(al[r], bh[cur], zq, 0, 0, 0);
                cl = __builtin_amdgcn_mfma_f32_16x16x32_f16(ah[r], bl[cur], cl, 0, 0, 0);
                #pragma unroll
                for (int e = 0; e < 4; ++e) {
                    float f = __builtin_fmaf(cl[e], k12, cm[e]);
                    float e2 = __builtin_amdgcn_exp2f(f);
                    accf[r][e] = __builtin_fmaf(e2, pfv[cur], accf[r][e]); // v_fmac
                }
            }
            yp += 64;   // one tile = 2048 B; uniform s_add on scalar pipe
            bp += 16;   // 64 B
        }
        #pragma unroll
        for (int r = 0; r < RI; ++r)
            #pragma unroll
            for (int e = 0; e < 4; ++e) accd[r][e] += (double)accf[r][e];
    }

    // sum the 16 j-columns: fp64 butterfly across the 16-lane col groups
    #pragma unroll
    for (int r = 0; r < RI; ++r) {
        #pragma unroll
        for (int e = 0; e < 4; ++e) {
            double v = accd[r][e];
            v += __shfl_xor(v, 1, 64);
            v += __shfl_xor(v, 2, 64);
            v += __shfl_xor(v, 4, 64);
            v += __shfl_xor(v, 8, 64);
            if (c15 == 0) {
                int row = (itbase + r) * 16 + (lane >> 4) * 4 + e;
                atomicAdd(&acc[row], v);   // fp64, JSPLIT writers per row
            }
        }
    }
}

__global__ __launch_bounds__(BLK) void rbf_finish(
    const double* __restrict__ acc, const double* __restrict__ scale,
    float* __restrict__ out, int n)
{
    int i = blockIdx.x * BLK + threadIdx.x;
    if (i < n) out[i] = (float)(acc[i] * scale[i]);
}

extern "C" void kernel_launch(void* const* d_in, const int* in_sizes, int n_in,
                              void* d_out, int out_size, void* d_ws, size_t ws_size,
                              hipStream_t stream)
{
    const float* ls = (const float*)d_in[0];
    const float* x  = (const float*)d_in[1];
    const float* y  = (const float*)d_in[2];
    const int n = in_sizes[1] / DIM;   // 32768
    const int m = in_sizes[2] / DIM;   // 32768
    float* out = (float*)d_out;

    // ws layout (ORDER MATTERS — one-past-end prefetches must stay in ws):
    //   acc[n] f64 | scale[n] f64 | pf[m] f32 | yhl | xhl   (~8.6 MB)
    char* ws = (char*)d_ws;
    double* acc   = (double*)ws;
    double* scale = acc + n;
    float*  pf    = (float*)(scale + n);
    hl16*   yhl   = (hl16*)(pf + m);
    hl16*   xhl   = yhl + (size_t)(m / 16) * 64;

    const int nm = (n > m) ? n : m;
    rbf_prep<<<(nm + BLK - 1) / BLK, BLK, 0, stream>>>(
        ls, x, y, n, m, acc, scale, pf, xhl, yhl);

    const int chunk = m / JSPLIT;                 // 2048
    dim3 grid(n / (16 * ITPB), JSPLIT);           // 128 x 16
    rbf_main<<<grid, BLK, 0, stream>>>(xhl, yhl, pf, acc, chunk);

    rbf_finish<<<(n + BLK - 1) / BLK, BLK, 0, stream>>>(acc, scale, out, n);
}

// Round 16
// 270.923 us; speedup vs baseline: 1.3797x; 1.0301x over previous
//
#include <hip/hip_runtime.h>
#include <math.h>

#define DIM 32
#define BLK 256
#define JSPLIT 16   // j-chunks -> grid.y ; 16 fp64-atomic writers per out row
#define RI   8      // i-tiles per wave (128 rows) -> 2048 pairs per wave-jtile
#define ITPB (4*RI) // i-tiles per block (32 tiles = 512 rows)
#define GTT  32     // j-tiles between fp32->fp64 flushes (512 j)

typedef _Float16 half8 __attribute__((ext_vector_type(8)));
typedef float    f32x4 __attribute__((ext_vector_type(4)));

struct hl16 { half8 h; half8 l; };   // 32 B fragment record (hi + lo plane)

// out[i] = 2^(c2*||x_i||^2) * sum_j pf_j * 2^(<mf*x_i, y_j> - 64)
//   where pf_j = 2^(c2*||y_j||^2 + 64)  (fp64-computed in prep, fp32 stored)
//   c2 = -ls*log2(e) (fp64, exact per-i factor in fp64 finish kernel)
//   f16 hi/lo split (lo plane *2^12 to stay f16-normal):
//     cm = Ah*Bh + (-64 quad) ; cl = Ah*Bl + Al*Bh ; f = fma(cl,2^-12,cm)
//     accf += exp2(f) * pf   (v_fmac; -64 bias keeps 2^f in fp32 range)
//   fp32 partials -> fp64 every GTT tiles; fp64 atomics.
// R15 = R14 (220 us main, WIN) + RI 4->8 (B-side work & per-step stall
//   bubbles amortize over 2x pairs; ~128 arch VGPR + accd in AGPR fits the
//   (256,2) budget) + prep split: x-rows and y-rows in DIFFERENT blocks
//   (R14 prep ran 128 blocks with x+y serialized per thread — half the CUs
//   idle; total-main has been a flat 58 us since R9).

__global__ __launch_bounds__(BLK) void rbf_prep(
    const float* __restrict__ lsp, const float* __restrict__ x,
    const float* __restrict__ y, int n, int m, int xblocks,
    double* __restrict__ acc, double* __restrict__ scale,
    float* __restrict__ pf, hl16* __restrict__ xhl, hl16* __restrict__ yhl)
{
    const double c2 = -(double)lsp[0] * 1.4426950408889634074; // -ls*log2(e)
    if ((int)blockIdx.x < xblocks) {
        const int i = blockIdx.x * BLK + threadIdx.x;
        if (i >= n) return;
        const float mf = (float)(-2.0 * c2);
        const float* xp = x + (size_t)i * DIM;
        double xs = 0.0;
        #pragma unroll
        for (int d = 0; d < DIM; ++d) { double v = (double)xp[d]; xs = fma(v, v, xs); }
        acc[i] = 0.0;
        scale[i] = exp2(c2 * xs);
        const int it = i >> 4, r15 = i & 15;
        #pragma unroll
        for (int q = 0; q < 4; ++q) {
            half8 hh, hl;
            #pragma unroll
            for (int d = 0; d < 8; ++d) {
                float v = xp[q * 8 + d] * mf;
                _Float16 h = (_Float16)v;
                hh[d] = h;
                hl[d] = (_Float16)((v - (float)h) * 4096.0f);
            }
            xhl[it * 64 + q * 16 + r15].h = hh;
            xhl[it * 64 + q * 16 + r15].l = hl;
        }
    } else {
        const int i = (blockIdx.x - xblocks) * BLK + threadIdx.x;
        if (i >= m) return;
        const float* yp = y + (size_t)i * DIM;
        double ys = 0.0;
        #pragma unroll
        for (int d = 0; d < DIM; ++d) { double v = (double)yp[d]; ys = fma(v, v, ys); }
        pf[i] = (float)exp2(c2 * ys + 64.0);   // 2^(bf+64), fp64-accurate
        const int it = i >> 4, r15 = i & 15;
        #pragma unroll
        for (int q = 0; q < 4; ++q) {
            half8 hh, hl;
            #pragma unroll
            for (int d = 0; d < 8; ++d) {
                float v = yp[q * 8 + d];
                _Float16 h = (_Float16)v;
                hh[d] = h;
                hl[d] = (_Float16)((v - (float)h) * 4096.0f);
            }
            yhl[it * 64 + q * 16 + r15].h = hh;
            yhl[it * 64 + q * 16 + r15].l = hl;
        }
    }
}

__global__ __launch_bounds__(BLK, 2) void rbf_main(
    const hl16* __restrict__ xhl, const hl16* __restrict__ yhl,
    const float* __restrict__ pfq, double* __restrict__ acc, int chunk_j)
{
    const int lane = threadIdx.x & 63;
    const int wave = threadIdx.x >> 6;
    const int itbase = blockIdx.x * ITPB + wave * RI;
    const int c15 = lane & 15;

    half8 ah[RI], al[RI];
    #pragma unroll
    for (int r = 0; r < RI; ++r) {
        ah[r] = xhl[(itbase + r) * 64 + lane].h;
        al[r] = xhl[(itbase + r) * 64 + lane].l;
    }

    const int jt0 = (blockIdx.y * chunk_j) >> 4;
    const int njt = chunk_j >> 4;                 // 128 j-tiles per chunk

    const f32x4 zq = {0.0f, 0.0f, 0.0f, 0.0f};            // persistent zero C
    const f32x4 nq = {-64.0f, -64.0f, -64.0f, -64.0f};    // persistent bias C
    const float k12 = 0x1p-12f;

    double accd[RI][4];
    #pragma unroll
    for (int r = 0; r < RI; ++r)
        #pragma unroll
        for (int e = 0; e < 4; ++e) accd[r][e] = 0.0;

    // uniform-pointer-bump addressing: fixed per-lane vaddr; bases bumped
    // one tile per step on the scalar pipe; load offsets imm {0,16,2048,2064}
    const hl16*  __restrict__ yp = yhl + (size_t)jt0 * 64;   // uniform base
    const float* __restrict__ bp = pfq + jt0 * 16;           // uniform base

    // 2-slot parity double-buffered B fragments
    half8 bh[2], bl[2];
    float pfv[2];
    bh[0] = yp[lane].h;
    bl[0] = yp[lane].l;
    pfv[0] = bp[c15];

    for (int g = 0; g < njt / GTT; ++g) {
        float accf[RI][4];
        #pragma unroll
        for (int r = 0; r < RI; ++r)
            #pragma unroll
            for (int e = 0; e < 4; ++e) accf[r][e] = 0.0f;

        #pragma unroll
        for (int tt = 0; tt < GTT; ++tt) {
            const int cur = tt & 1, nxt = cur ^ 1;
            // prefetch next tile (last prefetch of the last group reads one
            // tile past the chunk — never consumed; ws layout keeps it in ws)
            bh[nxt] = yp[64 + lane].h;
            bl[nxt] = yp[64 + lane].l;
            pfv[nxt] = bp[16 + c15];

            #pragma unroll
            for (int r = 0; r < RI; ++r) {
                f32x4 cm = __builtin_amdgcn_mfma_f32_16x16x32_f16(ah[r], bh[cur], nq, 0, 0, 0);
                f32x4 cl = __builtin_amdgcn_mfma_f32_16x16x32_f16(al[r], bh[cur], zq, 0, 0, 0);
                cl = __builtin_amdgcn_mfma_f32_16x16x32_f16(ah[r], bl[cur], cl, 0, 0, 0);
                #pragma unroll
                for (int e = 0; e < 4; ++e) {
                    float f = __builtin_fmaf(cl[e], k12, cm[e]);
                    float e2 = __builtin_amdgcn_exp2f(f);
                    accf[r][e] = __builtin_fmaf(e2, pfv[cur], accf[r][e]); // v_fmac
                }
            }
            yp += 64;   // one tile = 2048 B; uniform s_add on scalar pipe
            bp += 16;   // 64 B
        }
        #pragma unroll
        for (int r = 0; r < RI; ++r)
            #pragma unroll
            for (int e = 0; e < 4; ++e) accd[r][e] += (double)accf[r][e];
    }

    // sum the 16 j-columns: fp64 butterfly across the 16-lane col groups
    #pragma unroll
    for (int r = 0; r < RI; ++r) {
        #pragma unroll
        for (int e = 0; e < 4; ++e) {
            double v = accd[r][e];
            v += __shfl_xor(v, 1, 64);
            v += __shfl_xor(v, 2, 64);
            v += __shfl_xor(v, 4, 64);
            v += __shfl_xor(v, 8, 64);
            if (c15 == 0) {
                int row = (itbase + r) * 16 + (lane >> 4) * 4 + e;
                atomicAdd(&acc[row], v);   // fp64, JSPLIT writers per row
            }
        }
    }
}

__global__ __launch_bounds__(BLK) void rbf_finish(
    const double* __restrict__ acc, const double* __restrict__ scale,
    float* __restrict__ out, int n)
{
    int i = blockIdx.x * BLK + threadIdx.x;
    if (i < n) out[i] = (float)(acc[i] * scale[i]);
}

extern "C" void kernel_launch(void* const* d_in, const int* in_sizes, int n_in,
                              void* d_out, int out_size, void* d_ws, size_t ws_size,
                              hipStream_t stream)
{
    const float* ls = (const float*)d_in[0];
    const float* x  = (const float*)d_in[1];
    const float* y  = (const float*)d_in[2];
    const int n = in_sizes[1] / DIM;   // 32768
    const int m = in_sizes[2] / DIM;   // 32768
    float* out = (float*)d_out;

    // ws layout (ORDER MATTERS — one-past-end prefetches must stay in ws):
    //   acc[n] f64 | scale[n] f64 | pf[m] f32 | yhl | xhl   (~8.6 MB)
    char* ws = (char*)d_ws;
    double* acc   = (double*)ws;
    double* scale = acc + n;
    float*  pf    = (float*)(scale + n);
    hl16*   yhl   = (hl16*)(pf + m);
    hl16*   xhl   = yhl + (size_t)(m / 16) * 64;

    const int xblocks = (n + BLK - 1) / BLK;      // 128
    const int yblocks = (m + BLK - 1) / BLK;      // 128
    rbf_prep<<<xblocks + yblocks, BLK, 0, stream>>>(
        ls, x, y, n, m, xblocks, acc, scale, pf, xhl, yhl);

    const int chunk = m / JSPLIT;                 // 2048
    dim3 grid(n / (16 * ITPB), JSPLIT);           // 64 x 16
    rbf_main<<<grid, BLK, 0, stream>>>(xhl, yhl, pf, acc, chunk);

    rbf_finish<<<(n + BLK - 1) / BLK, BLK, 0, stream>>>(acc, scale, out, n);
}

// Round 17
// 270.272 us; speedup vs baseline: 1.3830x; 1.0024x over previous
//
#include <hip/hip_runtime.h>
#include <math.h>

#define DIM 32
#define BLK 256
#define JSPLIT 16   // j-chunks -> grid.y ; 16 fp64-atomic writers per out row
#define RI   4      // i-tiles per wave (64 rows) — R14 sweet spot: 64 VGPR, 3 blk/CU
#define ITPB (4*RI) // i-tiles per block (16 tiles = 256 rows)
#define GTT  32     // j-tiles between fp32->fp64 flushes (512 j)

typedef _Float16 half8 __attribute__((ext_vector_type(8)));
typedef float    f32x4 __attribute__((ext_vector_type(4)));

struct hl16 { half8 h; half8 l; };   // 32 B fragment record (hi + lo plane)

// out[i] = 2^(c2*||x_i||^2) * sum_j pf_j * 2^(<mf*x_i, y_j> - 64)
//   where pf_j = 2^(c2*||y_j||^2 + 64)  (fp64-computed in prep, fp32 stored)
//   c2 = -ls*log2(e) (fp64, exact per-i factor in fp64 finish kernel)
//   f16 hi/lo split (lo plane *2^12 to stay f16-normal):
//     cm = Ah*Bh + (-64 quad) ; cl = Ah*Bl + Al*Bh ; f = fma(cl,2^-12,cm)
//     accf += exp2(f) * pf   (v_fmac; -64 bias keeps 2^f in fp32 range)
//   fp32 partials -> fp64 every GTT tiles; fp64 atomics.
// R16 = consolidation: R14 main (RI=4 — RI=8 regressed via occupancy cliff
//   at 108 VGPR: 3->2 blocks/CU; RI=4's 64-VGPR keeps 12 waves/CU) +
//   R15 split prep (x and y in different blocks — banked ~19 us).

__global__ __launch_bounds__(BLK) void rbf_prep(
    const float* __restrict__ lsp, const float* __restrict__ x,
    const float* __restrict__ y, int n, int m, int xblocks,
    double* __restrict__ acc, double* __restrict__ scale,
    float* __restrict__ pf, hl16* __restrict__ xhl, hl16* __restrict__ yhl)
{
    const double c2 = -(double)lsp[0] * 1.4426950408889634074; // -ls*log2(e)
    if ((int)blockIdx.x < xblocks) {
        const int i = blockIdx.x * BLK + threadIdx.x;
        if (i >= n) return;
        const float mf = (float)(-2.0 * c2);
        const float* xp = x + (size_t)i * DIM;
        double xs = 0.0;
        #pragma unroll
        for (int d = 0; d < DIM; ++d) { double v = (double)xp[d]; xs = fma(v, v, xs); }
        acc[i] = 0.0;
        scale[i] = exp2(c2 * xs);
        const int it = i >> 4, r15 = i & 15;
        #pragma unroll
        for (int q = 0; q < 4; ++q) {
            half8 hh, hl;
            #pragma unroll
            for (int d = 0; d < 8; ++d) {
                float v = xp[q * 8 + d] * mf;
                _Float16 h = (_Float16)v;
                hh[d] = h;
                hl[d] = (_Float16)((v - (float)h) * 4096.0f);
            }
            xhl[it * 64 + q * 16 + r15].h = hh;
            xhl[it * 64 + q * 16 + r15].l = hl;
        }
    } else {
        const int i = (blockIdx.x - xblocks) * BLK + threadIdx.x;
        if (i >= m) return;
        const float* yp = y + (size_t)i * DIM;
        double ys = 0.0;
        #pragma unroll
        for (int d = 0; d < DIM; ++d) { double v = (double)yp[d]; ys = fma(v, v, ys); }
        pf[i] = (float)exp2(c2 * ys + 64.0);   // 2^(bf+64), fp64-accurate
        const int it = i >> 4, r15 = i & 15;
        #pragma unroll
        for (int q = 0; q < 4; ++q) {
            half8 hh, hl;
            #pragma unroll
            for (int d = 0; d < 8; ++d) {
                float v = yp[q * 8 + d];
                _Float16 h = (_Float16)v;
                hh[d] = h;
                hl[d] = (_Float16)((v - (float)h) * 4096.0f);
            }
            yhl[it * 64 + q * 16 + r15].h = hh;
            yhl[it * 64 + q * 16 + r15].l = hl;
        }
    }
}

__global__ __launch_bounds__(BLK, 2) void rbf_main(
    const hl16* __restrict__ xhl, const hl16* __restrict__ yhl,
    const float* __restrict__ pfq, double* __restrict__ acc, int chunk_j)
{
    const int lane = threadIdx.x & 63;
    const int wave = threadIdx.x >> 6;
    const int itbase = blockIdx.x * ITPB + wave * RI;
    const int c15 = lane & 15;

    half8 ah[RI], al[RI];
    #pragma unroll
    for (int r = 0; r < RI; ++r) {
        ah[r] = xhl[(itbase + r) * 64 + lane].h;
        al[r] = xhl[(itbase + r) * 64 + lane].l;
    }

    const int jt0 = (blockIdx.y * chunk_j) >> 4;
    const int njt = chunk_j >> 4;                 // 128 j-tiles per chunk

    const f32x4 zq = {0.0f, 0.0f, 0.0f, 0.0f};            // persistent zero C
    const f32x4 nq = {-64.0f, -64.0f, -64.0f, -64.0f};    // persistent bias C
    const float k12 = 0x1p-12f;

    double accd[RI][4];
    #pragma unroll
    for (int r = 0; r < RI; ++r)
        #pragma unroll
        for (int e = 0; e < 4; ++e) accd[r][e] = 0.0;

    // uniform-pointer-bump addressing: fixed per-lane vaddr; bases bumped
    // one tile per step on the scalar pipe; load offsets imm {0,16,2048,2064}
    const hl16*  __restrict__ yp = yhl + (size_t)jt0 * 64;   // uniform base
    const float* __restrict__ bp = pfq + jt0 * 16;           // uniform base

    // 2-slot parity double-buffered B fragments
    half8 bh[2], bl[2];
    float pfv[2];
    bh[0] = yp[lane].h;
    bl[0] = yp[lane].l;
    pfv[0] = bp[c15];

    for (int g = 0; g < njt / GTT; ++g) {
        float accf[RI][4];
        #pragma unroll
        for (int r = 0; r < RI; ++r)
            #pragma unroll
            for (int e = 0; e < 4; ++e) accf[r][e] = 0.0f;

        #pragma unroll
        for (int tt = 0; tt < GTT; ++tt) {
            const int cur = tt & 1, nxt = cur ^ 1;
            // prefetch next tile (last prefetch of the last group reads one
            // tile past the chunk — never consumed; ws layout keeps it in ws)
            bh[nxt] = yp[64 + lane].h;
            bl[nxt] = yp[64 + lane].l;
            pfv[nxt] = bp[16 + c15];

            #pragma unroll
            for (int r = 0; r < RI; ++r) {
                f32x4 cm = __builtin_amdgcn_mfma_f32_16x16x32_f16(ah[r], bh[cur], nq, 0, 0, 0);
                f32x4 cl = __builtin_amdgcn_mfma_f32_16x16x32_f16(al[r], bh[cur], zq, 0, 0, 0);
                cl = __builtin_amdgcn_mfma_f32_16x16x32_f16(ah[r], bl[cur], cl, 0, 0, 0);
                #pragma unroll
                for (int e = 0; e < 4; ++e) {
                    float f = __builtin_fmaf(cl[e], k12, cm[e]);
                    float e2 = __builtin_amdgcn_exp2f(f);
                    accf[r][e] = __builtin_fmaf(e2, pfv[cur], accf[r][e]); // v_fmac
                }
            }
            yp += 64;   // one tile = 2048 B; uniform s_add on scalar pipe
            bp += 16;   // 64 B
        }
        #pragma unroll
        for (int r = 0; r < RI; ++r)
            #pragma unroll
            for (int e = 0; e < 4; ++e) accd[r][e] += (double)accf[r][e];
    }

    // sum the 16 j-columns: fp64 butterfly across the 16-lane col groups
    #pragma unroll
    for (int r = 0; r < RI; ++r) {
        #pragma unroll
        for (int e = 0; e < 4; ++e) {
            double v = accd[r][e];
            v += __shfl_xor(v, 1, 64);
            v += __shfl_xor(v, 2, 64);
            v += __shfl_xor(v, 4, 64);
            v += __shfl_xor(v, 8, 64);
            if (c15 == 0) {
                int row = (itbase + r) * 16 + (lane >> 4) * 4 + e;
                atomicAdd(&acc[row], v);   // fp64, JSPLIT writers per row
            }
        }
    }
}

__global__ __launch_bounds__(BLK) void rbf_finish(
    const double* __restrict__ acc, const double* __restrict__ scale,
    float* __restrict__ out, int n)
{
    int i = blockIdx.x * BLK + threadIdx.x;
    if (i < n) out[i] = (float)(acc[i] * scale[i]);
}

extern "C" void kernel_launch(void* const* d_in, const int* in_sizes, int n_in,
                              void* d_out, int out_size, void* d_ws, size_t ws_size,
                              hipStream_t stream)
{
    const float* ls = (const float*)d_in[0];
    const float* x  = (const float*)d_in[1];
    const float* y  = (const float*)d_in[2];
    const int n = in_sizes[1] / DIM;   // 32768
    const int m = in_sizes[2] / DIM;   // 32768
    float* out = (float*)d_out;

    // ws layout (ORDER MATTERS — one-past-end prefetches must stay in ws):
    //   acc[n] f64 | scale[n] f64 | pf[m] f32 | yhl | xhl   (~8.6 MB)
    char* ws = (char*)d_ws;
    double* acc   = (double*)ws;
    double* scale = acc + n;
    float*  pf    = (float*)(scale + n);
    hl16*   yhl   = (hl16*)(pf + m);
    hl16*   xhl   = yhl + (size_t)(m / 16) * 64;

    const int xblocks = (n + BLK - 1) / BLK;      // 128
    const int yblocks = (m + BLK - 1) / BLK;      // 128
    rbf_prep<<<xblocks + yblocks, BLK, 0, stream>>>(
        ls, x, y, n, m, xblocks, acc, scale, pf, xhl, yhl);

    const int chunk = m / JSPLIT;                 // 2048
    dim3 grid(n / (16 * ITPB), JSPLIT);           // 128 x 16
    rbf_main<<<grid, BLK, 0, stream>>>(xhl, yhl, pf, acc, chunk);

    rbf_finish<<<(n + BLK - 1) / BLK, BLK, 0, stream>>>(acc, scale, out, n);
}